// Round 6
// baseline (90.515 us; speedup 1.0000x reference)
//
#include <hip/hip_runtime.h>
#include <stdint.h>

// Problem geometry (fixed by setup_inputs)
#define HW    1024
#define BATCH 32
#define TR    16                 // rows per block tile
#define HR    (TR + 6)           // 22: tile rows + 3-row halo each side
#define WN    32                 // u32 words per row (bit = col)
#define TILES (HW / TR)          // 64 tiles per image
#define NBLK  (BATCH * TILES)    // 2048 blocks

// weight constants: 1 - tanh(d/3) for d = 1,2,3
#define W1 0.6784872f
#define W2 0.4172171f
#define W3 0.2384058f

typedef float v2f __attribute__((ext_vector_type(2)));

static __device__ __forceinline__ v2f pk_fma(v2f a, v2f b, v2f c) {
    return __builtin_elementwise_fma(a, b, c);
}

// ---------------------------------------------------------------------------
// k_bits: targ -> packed distance planes in global ws + per-block sum(t),sum(w)
// ---------------------------------------------------------------------------
__global__ __launch_bounds__(256) void k_bits(const float* __restrict__ targ,
                                              uint4* __restrict__ plane_g,
                                              float* __restrict__ ws) {
    __shared__ uint32_t fg[HR][WN];   // raw foreground bits; halo outside image = 0
    __shared__ float red[4][2];

    const int bid  = blockIdx.x;
    // XCD-contiguous swizzle: all tiles of an image on one XCD (halo L2 reuse)
    const int blk  = (bid & 7) * (NBLK / 8) + (bid >> 3);
    const int b    = blk / TILES;
    const int tile = blk - b * TILES;
    const int r0   = tile * TR;
    const int tid  = threadIdx.x;
    const int lane = tid & 63;
    const int wid  = tid >> 6;

    // ---- phase A: float4 targ loads; 4 bits/lane; 8-lane OR-combine -> one word
    const float* tbase = targ + (size_t)b * HW * HW;
    for (int task = wid; task < HR * 4; task += 4) {
        const int row = task >> 2;       // 0..HR-1  (uniform per wave)
        const int g   = task & 3;        // 256-col group
        const int gr  = r0 - 3 + row;
        uint32_t v = 0u;
        if (gr >= 0 && gr < HW) {        // wave-uniform branch
            const float4 t4 = *(const float4*)(tbase + (size_t)gr * HW + (g << 8) + (lane << 2));
            // targets are exactly 0.0f / 1.0f -> bit 23 of the float pattern
            const uint32_t u0 = __float_as_uint(t4.x), u1 = __float_as_uint(t4.y);
            const uint32_t u2 = __float_as_uint(t4.z), u3 = __float_as_uint(t4.w);
            const uint32_t n = ((u0 >> 23) & 1u) | ((u1 >> 22) & 2u)
                             | ((u2 >> 21) & 4u) | ((u3 >> 20) & 8u);
            v = n << ((lane & 7) << 2);
        }
        v |= __shfl_xor(v, 1);
        v |= __shfl_xor(v, 2);
        v |= __shfl_xor(v, 4);
        if ((lane & 7) == 0) fg[row][(g << 3) + (lane >> 3)] = v;
    }
    __syncthreads();

    // ---- phase B: planes from fg (vertical-first separable box-OR) -> global;
    // word-parallel popcounts give exact sum(t), sum(w).
    uint32_t ct = 0, c1 = 0, c2 = 0, c3 = 0;
    for (int i = tid; i < TR * WN; i += 256) {
        const int row = i >> 5;
        const int wz  = i & 31;
        const int hr  = row + 3;
        uint32_t v1c = 0, v2c = 0, v3c = 0, v1p = 0, v2p = 0, v3p = 0, v1n = 0, v2n = 0, v3n = 0;
        uint32_t u1c = 0, u2c = 0, u3c = 0, u1p = 0, u2p = 0, u3p = 0, u1n = 0, u2n = 0, u3n = 0;
        uint32_t tw = 0;
#pragma unroll
        for (int dr = -3; dr <= 3; ++dr) {
            const int r  = hr + dr;
            const int gr = r0 - 3 + r;
            const bool valid = (gr >= 0) && (gr < HW);
            const uint32_t c = fg[r][wz];
            const uint32_t p = (wz > 0)  ? fg[r][wz - 1] : 0u;
            const uint32_t n = (wz < 31) ? fg[r][wz + 1] : 0u;
            // background = complement inside the image only (SAME padding = empty)
            const uint32_t cb = valid ? ~c : 0u;
            const uint32_t pb = (valid && wz > 0)  ? ~p : 0u;
            const uint32_t nb = (valid && wz < 31) ? ~n : 0u;
            if (dr == 0) tw = c;
            v3c |= c;  v3p |= p;  v3n |= n;
            u3c |= cb; u3p |= pb; u3n |= nb;
            if (dr >= -2 && dr <= 2) {
                v2c |= c;  v2p |= p;  v2n |= n;
                u2c |= cb; u2p |= pb; u2n |= nb;
            }
            if (dr >= -1 && dr <= 1) {
                v1c |= c;  v1p |= p;  v1n |= n;
                u1c |= cb; u1p |= pb; u1n |= nb;
            }
        }
        const uint32_t d1f = v1c | (v1c << 1) | (v1p >> 31) | (v1c >> 1) | (v1n << 31);
        const uint32_t d2f = v2c | (v2c << 1) | (v2p >> 31) | (v2c >> 1) | (v2n << 31)
                                 | (v2c << 2) | (v2p >> 30) | (v2c >> 2) | (v2n << 30);
        const uint32_t d3f = v3c | (v3c << 1) | (v3p >> 31) | (v3c >> 1) | (v3n << 31)
                                 | (v3c << 2) | (v3p >> 30) | (v3c >> 2) | (v3n << 30)
                                 | (v3c << 3) | (v3p >> 29) | (v3c >> 3) | (v3n << 29);
        const uint32_t d1b = u1c | (u1c << 1) | (u1p >> 31) | (u1c >> 1) | (u1n << 31);
        const uint32_t d2b = u2c | (u2c << 1) | (u2p >> 31) | (u2c >> 1) | (u2n << 31)
                                 | (u2c << 2) | (u2p >> 30) | (u2c >> 2) | (u2n << 30);
        const uint32_t d3b = u3c | (u3c << 1) | (u3p >> 31) | (u3c >> 1) | (u3n << 31)
                                 | (u3c << 2) | (u3p >> 30) | (u3c >> 2) | (u3n << 30)
                                 | (u3c << 3) | (u3p >> 29) | (u3c >> 3) | (u3n << 29);
        uint4 pl;
        pl.x = tw;                                  // target bits
        pl.y = (tw & d1b) | (~tw & d1f);            // dist<=1 to opposite class
        pl.z = (tw & d2b) | (~tw & d2f);            // dist<=2
        pl.w = (tw & d3b) | (~tw & d3f);            // dist<=3  (nested)
        plane_g[((size_t)b * HW + r0 + row) * WN + wz] = pl;
        ct += __popc(pl.x);
        c1 += __popc(pl.y);
        c2 += __popc(pl.z);
        c3 += __popc(pl.w);
    }

    // block-reduce the two exact sums (integer counts -> float, < 2^24: exact)
    float vt = (float)ct;
    float vw = fmaf((float)c1, W1 - W2, fmaf((float)c2, W2 - W3, (float)c3 * W3));
#pragma unroll
    for (int off = 1; off < 64; off <<= 1) {
        vt += __shfl_xor(vt, off);
        vw += __shfl_xor(vw, off);
    }
    if (lane == 0) { red[wid][0] = vt; red[wid][1] = vw; }
    __syncthreads();
    if (tid < 2) {
        float s = red[0][tid] + red[1][tid] + red[2][tid] + red[3][tid];
        ws[(2 + tid) * NBLK + blk] = s;    // q=2: sum(t), q=3: sum(w)
    }
}

// ---------------------------------------------------------------------------
// k_pix: pred + planes -> 5 streaming sums. No LDS tile, no phase barriers.
// ---------------------------------------------------------------------------
__global__ __launch_bounds__(256) void k_pix(const float* __restrict__ pred,
                                             const uint4* __restrict__ plane_g,
                                             float* __restrict__ ws) {
    __shared__ float red[4][5];

    const int bid  = blockIdx.x;
    const int blk  = (bid & 7) * (NBLK / 8) + (bid >> 3);   // match k_bits XCD map
    const int b    = blk / TILES;
    const int tile = blk - b * TILES;
    const int r0   = tile * TR;
    const int tid  = threadIdx.x;
    const int lane = tid & 63;
    const int wid  = tid >> 6;

    const float4* p4 = (const float4*)(pred + (size_t)b * HW * HW + (size_t)r0 * HW);
    const uint4*  pg = plane_g + ((size_t)b * HW + r0) * WN;
    const int wz = tid >> 3;             // word index for cols tid*4..tid*4+3
    const int sh = (tid & 7) << 2;       // bit offset of col tid*4 within the word

    const v2f dW12 = {W1 - W2, W1 - W2};
    const v2f dW23 = {W2 - W3, W2 - W3};
    const v2f cW3  = {W3, W3};
    const v2f kM2  = {-2.f, -2.f};
    const v2f kP1  = {1.f, 1.f};
    const v2f kMH  = {-0.5f, -0.5f};
    const v2f k34  = {0.75f, 0.75f};

    v2f a_pt = {0.f, 0.f}, a_p = {0.f, 0.f}, a_bw = {0.f, 0.f},
        a_ce = {0.f, 0.f}, a_f = {0.f, 0.f};

    // depth-2 prefetch on both streams
    float4 xa = p4[tid];
    float4 xb = p4[256 + tid];
    uint4  qa = pg[wz];
    uint4  qb = pg[WN + wz];

    for (int rr = 0; rr < TR; ++rr) {
        const float4 cur = xa;
        const uint4  pl  = qa;
        xa = xb; qa = qb;
        if (rr + 2 < TR) {
            xb = p4[(rr + 2) * 256 + tid];
            qb = pg[(rr + 2) * WN + wz];
        }
#pragma unroll
        for (int h = 0; h < 2; ++h) {    // pixel pair (2h, 2h+1)
            v2f x;
            x.x = (h == 0) ? cur.x : cur.z;
            x.y = (h == 0) ? cur.y : cur.w;
            const int q0 = sh + (h << 1);

            v2f tf = {(float)((pl.x >> q0) & 1u), (float)((pl.x >> (q0 + 1)) & 1u)};
            v2f f1 = {(float)((pl.y >> q0) & 1u), (float)((pl.y >> (q0 + 1)) & 1u)};
            v2f f2 = {(float)((pl.z >> q0) & 1u), (float)((pl.z >> (q0 + 1)) & 1u)};
            v2f f3 = {(float)((pl.w >> q0) & 1u), (float)((pl.w >> (q0 + 1)) & 1u)};

            v2f ea;
            ea.x = fabsf(x.x) * -1.4426950408889634f;
            ea.y = fabsf(x.y) * -1.4426950408889634f;
            v2f e   = {__builtin_amdgcn_exp2f(ea.x), __builtin_amdgcn_exp2f(ea.y)};
            v2f opl = e + 1.0f;
            v2f inv = {__builtin_amdgcn_rcpf(opl.x), __builtin_amdgcn_rcpf(opl.y)};
            v2f lg  = {__builtin_amdgcn_logf(opl.x), __builtin_amdgcn_logf(opl.y)};
            v2f l1p = lg * 0.6931471805599453f;      // log1p(exp(-|x|))
            v2f pm  = 1.0f - inv;
            v2f p;                                   // sigmoid(x)
            p.x = (x.x >= 0.f) ? inv.x : pm.x;
            p.y = (x.y >= 0.f) ? inv.y : pm.y;

            v2f mx;
            mx.x = fmaxf(x.x, 0.f);
            mx.y = fmaxf(x.y, 0.f);
            v2f ce  = pk_fma(x, -tf, mx + l1p);      // stable BCE-with-logits

            v2f m2p = pk_fma(p, kM2, kP1);
            v2f omp = pk_fma(tf, m2p, p);            // 1 - p_t
            v2f at  = pk_fma(tf, kMH, k34);
            v2f o2  = omp * omp;
            a_f  = pk_fma(o2 * at, ce, a_f);         // focal

            v2f w = pk_fma(f1, dW12, pk_fma(f2, dW23, f3 * cW3));
            a_bw = pk_fma(w, ce, a_bw);
            a_ce += ce;
            a_p  += p;
            a_pt  = pk_fma(tf, p, a_pt);
        }
    }

    // deterministic block reduction (same tree shape as before)
    float v[5];
    v[0] = a_pt.x + a_pt.y;
    v[1] = a_p.x + a_p.y;
    v[2] = a_bw.x + a_bw.y;
    v[3] = a_ce.x + a_ce.y;
    v[4] = a_f.x + a_f.y;
#pragma unroll
    for (int off = 1; off < 64; off <<= 1) {
#pragma unroll
        for (int j = 0; j < 5; ++j) v[j] += __shfl_xor(v[j], off);
    }
    if (lane == 0) {
#pragma unroll
        for (int j = 0; j < 5; ++j) red[wid][j] = v[j];
    }
    __syncthreads();
    if (tid < 5) {
        float s = red[0][tid] + red[1][tid] + red[2][tid] + red[3][tid];
        const int q = (tid == 0) ? 0 : (tid == 1) ? 1 : (tid == 2) ? 4 : (tid == 3) ? 5 : 6;
        ws[q * NBLK + blk] = s;
    }
}

// merged per-batch reduction + final scalar math (one launch)
__global__ __launch_bounds__(256) void k_tail(const float* __restrict__ ws,
                                              const float* __restrict__ lv,
                                              float* __restrict__ out) {
    __shared__ float res[7][BATCH];
    const int tid = threadIdx.x;
    const int b   = tid >> 3;          // batch 0..31
    const int g   = tid & 7;           // 8 threads per batch
#pragma unroll
    for (int q = 0; q < 7; ++q) {
        float s = 0.f;
#pragma unroll
        for (int i = 0; i < TILES / 8; ++i) s += ws[q * NBLK + b * TILES + g + i * 8];
        s += __shfl_xor(s, 1);
        s += __shfl_xor(s, 2);
        s += __shfl_xor(s, 4);
        if (g == 0) res[q][b] = s;
    }
    __syncthreads();
    if (tid < 32) {
        const float pt = res[0][tid];
        const float p  = res[1][tid];
        const float t  = res[2][tid];
        const float w  = res[3][tid];
        const float bw = res[4][tid];
        float d  = 1.f - (2.f * pt + 1.f) / (p + t + 1.f);
        float io = 1.f - (pt + 1e-6f) / (p + t - pt + 1e-6f);
        float bn = bw / fmaxf(w, 1.f);
        float ce = res[5][tid];
        float fo = res[6][tid];
#pragma unroll
        for (int off = 1; off < 32; off <<= 1) {
            d  += __shfl_xor(d, off);
            io += __shfl_xor(io, off);
            bn += __shfl_xor(bn, off);
            ce += __shfl_xor(ce, off);
            fo += __shfl_xor(fo, off);
        }
        if (tid == 0) {
            const float N = 33554432.f;   // 32*1024*1024
            float ls[5];
            ls[0] = ce / N;                        // ce
            ls[1] = d * (1.f / 32.f);              // dice
            ls[2] = 0.5f * fo / N;                 // focal
            ls[3] = 0.3f * io * (1.f / 32.f);      // iou
            ls[4] = 0.2f * bn * (1.f / 32.f);      // boundary
            float r[5], s = 0.f;
#pragma unroll
            for (int i = 0; i < 5; ++i) {
                r[i] = 1.f / (1.f + __expf(-lv[i] * (1.f / 1.5f)));
                s += r[i];
            }
            float tot = 0.f;
#pragma unroll
            for (int i = 0; i < 5; ++i) tot += (r[i] / s) * 5.f * ls[i];
            out[0] = tot;
        }
    }
}

extern "C" void kernel_launch(void* const* d_in, const int* in_sizes, int n_in,
                              void* d_out, int out_size, void* d_ws, size_t ws_size,
                              hipStream_t stream) {
    const float* pred = (const float*)d_in[0];
    const float* targ = (const float*)d_in[1];
    const float* lv   = (const float*)d_in[2];
    float* out = (float*)d_out;
    float* ws  = (float*)d_ws;                          // [7][NBLK] partials
    uint4* plane_g = (uint4*)(ws + 7 * NBLK);           // [BATCH*HW][WN] planes, 16.8 MB

    k_bits<<<NBLK, 256, 0, stream>>>(targ, plane_g, ws);
    k_pix <<<NBLK, 256, 0, stream>>>(pred, plane_g, ws);
    k_tail<<<1, 256, 0, stream>>>(ws, lv, out);
}

// Round 7
// 69.044 us; speedup vs baseline: 1.3110x; 1.3110x over previous
//
#include <hip/hip_runtime.h>
#include <stdint.h>

// Problem geometry (fixed by setup_inputs)
#define HW    1024
#define BATCH 32
#define TR    16                 // rows per block tile
#define HR    (TR + 6)           // 22: tile rows + 3-row halo each side
#define WN    32                 // u32 words per row (bit = col)
#define TILES (HW / TR)          // 64 tiles per image
#define NBLK  (BATCH * TILES)    // 2048 blocks
#define NTASK (HR * 128)         // 2816 byte-tasks per block (128 bytes/row)
#define TPT   (NTASK / 256)      // 11 tasks per thread

// weight constants: 1 - tanh(d/3) for d = 1,2,3
#define W1 0.6784872f
#define W2 0.4172171f
#define W3 0.2384058f

typedef float v2f __attribute__((ext_vector_type(2)));

static __device__ __forceinline__ v2f pk_fma(v2f a, v2f b, v2f c) {
    return __builtin_elementwise_fma(a, b, c);
}

__global__ __launch_bounds__(256) void k_main(const float* __restrict__ pred,
                                              const float* __restrict__ targ,
                                              float* __restrict__ ws) {
    // raw foreground bits (bit i of word w = col 32w+i); halo rows outside image = 0
    __shared__ uint32_t fg[HR][WN];
    // packed per-word planes: {t, dil1(opp), dil2(opp), dil3(opp)} selected per bit
    __shared__ uint4 plane[TR][WN];
    __shared__ float red[4][8];
    // total LDS: 2816 + 8192 + 128 = 11136 B -> 8 blocks/CU co-resident

    const int bid  = blockIdx.x;
    // XCD-contiguous swizzle: all 64 tiles of an image on one XCD (halo L2 reuse)
    const int blk  = (bid & 7) * (NBLK / 8) + (bid >> 3);
    const int b    = blk / TILES;
    const int tile = blk - b * TILES;
    const int r0   = tile * TR;
    const int tid  = threadIdx.x;
    const int lane = tid & 63;
    const int wid  = tid >> 6;

    // early pred prefetch: rides in flight across phases A and B
    const float4* p4 = (const float4*)(pred + (size_t)b * HW * HW + (size_t)r0 * HW);
    float4 xa = p4[tid];
    float4 xb = p4[256 + tid];

    // ---- phase A: ballot-free bit build. Task = 8 targ px -> 1 byte ds_write.
    // Batch-staged loads (2 tasks = 4 float4 in flight) keep the memory pipe full.
    const float* tbase = targ + (size_t)b * HW * HW;
    uint8_t* fg8 = (uint8_t*)&fg[0][0];
#pragma unroll
    for (int base = 0; base < TPT; base += 2) {
        float4 sa[2], sb[2];
        int    rw[2], by[2];
        bool   vv[2];
#pragma unroll
        for (int j = 0; j < 2; ++j) {
            if (base + j < TPT) {
                const int task = tid + (base + j) * 256;
                const int row  = task >> 7;        // 0..HR-1
                const int byt  = task & 127;       // byte within row (8 cols each)
                const int gr   = r0 - 3 + row;
                rw[j] = row; by[j] = byt;
                vv[j] = (gr >= 0) && (gr < HW);
                if (vv[j]) {
                    const float4* rp = (const float4*)(tbase + (size_t)gr * HW);
                    sa[j] = rp[byt * 2];
                    sb[j] = rp[byt * 2 + 1];
                }
            }
        }
#pragma unroll
        for (int j = 0; j < 2; ++j) {
            if (base + j < TPT) {
                uint32_t n = 0u;
                if (vv[j]) {
                    // targets are exactly 0.0f / 1.0f -> bit 23 of the float pattern
                    n  =  (__float_as_uint(sa[j].x) >> 23) & 1u;
                    n |= ((__float_as_uint(sa[j].y) >> 23) & 1u) << 1;
                    n |= ((__float_as_uint(sa[j].z) >> 23) & 1u) << 2;
                    n |= ((__float_as_uint(sa[j].w) >> 23) & 1u) << 3;
                    n |= ((__float_as_uint(sb[j].x) >> 23) & 1u) << 4;
                    n |= ((__float_as_uint(sb[j].y) >> 23) & 1u) << 5;
                    n |= ((__float_as_uint(sb[j].z) >> 23) & 1u) << 6;
                    n |= ((__float_as_uint(sb[j].w) >> 23) & 1u) << 7;
                }
                fg8[rw[j] * 128 + by[j]] = (uint8_t)n;   // independent byte write
            }
        }
    }
    __syncthreads();

    // ---- phase B: plane directly from fg, vertical-first separable box-OR.
    // Word-parallel popcounts give exact sum(t), sum(w) (hoisted out of phase C).
    uint32_t ct = 0, c1 = 0, c2 = 0, c3 = 0;
    for (int i = tid; i < TR * WN; i += 256) {
        const int row = i >> 5;
        const int wz  = i & 31;
        const int hr  = row + 3;
        uint32_t v1c = 0, v2c = 0, v3c = 0, v1p = 0, v2p = 0, v3p = 0, v1n = 0, v2n = 0, v3n = 0;
        uint32_t u1c = 0, u2c = 0, u3c = 0, u1p = 0, u2p = 0, u3p = 0, u1n = 0, u2n = 0, u3n = 0;
        uint32_t tw = 0;
#pragma unroll
        for (int dr = -3; dr <= 3; ++dr) {
            const int r  = hr + dr;
            const int gr = r0 - 3 + r;
            const bool valid = (gr >= 0) && (gr < HW);
            const uint32_t c = fg[r][wz];
            const uint32_t p = (wz > 0)  ? fg[r][wz - 1] : 0u;
            const uint32_t n = (wz < 31) ? fg[r][wz + 1] : 0u;
            // background = complement inside the image only (SAME padding = empty)
            const uint32_t cb = valid ? ~c : 0u;
            const uint32_t pb = (valid && wz > 0)  ? ~p : 0u;
            const uint32_t nb = (valid && wz < 31) ? ~n : 0u;
            if (dr == 0) tw = c;
            v3c |= c;  v3p |= p;  v3n |= n;
            u3c |= cb; u3p |= pb; u3n |= nb;
            if (dr >= -2 && dr <= 2) {
                v2c |= c;  v2p |= p;  v2n |= n;
                u2c |= cb; u2p |= pb; u2n |= nb;
            }
            if (dr >= -1 && dr <= 1) {
                v1c |= c;  v1p |= p;  v1n |= n;
                u1c |= cb; u1p |= pb; u1n |= nb;
            }
        }
        const uint32_t d1f = v1c | (v1c << 1) | (v1p >> 31) | (v1c >> 1) | (v1n << 31);
        const uint32_t d2f = v2c | (v2c << 1) | (v2p >> 31) | (v2c >> 1) | (v2n << 31)
                                 | (v2c << 2) | (v2p >> 30) | (v2c >> 2) | (v2n << 30);
        const uint32_t d3f = v3c | (v3c << 1) | (v3p >> 31) | (v3c >> 1) | (v3n << 31)
                                 | (v3c << 2) | (v3p >> 30) | (v3c >> 2) | (v3n << 30)
                                 | (v3c << 3) | (v3p >> 29) | (v3c >> 3) | (v3n << 29);
        const uint32_t d1b = u1c | (u1c << 1) | (u1p >> 31) | (u1c >> 1) | (u1n << 31);
        const uint32_t d2b = u2c | (u2c << 1) | (u2p >> 31) | (u2c >> 1) | (u2n << 31)
                                 | (u2c << 2) | (u2p >> 30) | (u2c >> 2) | (u2n << 30);
        const uint32_t d3b = u3c | (u3c << 1) | (u3p >> 31) | (u3c >> 1) | (u3n << 31)
                                 | (u3c << 2) | (u3p >> 30) | (u3c >> 2) | (u3n << 30)
                                 | (u3c << 3) | (u3p >> 29) | (u3c >> 3) | (u3n << 29);
        uint4 pl;
        pl.x = tw;                                  // target bits
        pl.y = (tw & d1b) | (~tw & d1f);            // dist<=1 to opposite class
        pl.z = (tw & d2b) | (~tw & d2f);            // dist<=2
        pl.w = (tw & d3b) | (~tw & d3f);            // dist<=3  (nested)
        plane[row][wz] = pl;
        ct += __popc(pl.x);
        c1 += __popc(pl.y);
        c2 += __popc(pl.z);
        c3 += __popc(pl.w);
    }
    __syncthreads();

    // ---- phase C: per-pixel math, packed-f32 pairs; depth-2 global prefetch
    v2f a_pt = {0.f, 0.f}, a_p = {0.f, 0.f}, a_bw = {0.f, 0.f},
        a_ce = {0.f, 0.f}, a_f = {0.f, 0.f};
    const int wz = tid >> 3;             // word index for cols tid*4..tid*4+3
    const int sh = (tid & 7) << 2;       // bit offset of col tid*4 within the word

    const v2f dW12 = {W1 - W2, W1 - W2};
    const v2f dW23 = {W2 - W3, W2 - W3};
    const v2f cW3  = {W3, W3};
    const v2f kM2  = {-2.f, -2.f};
    const v2f kP1  = {1.f, 1.f};
    const v2f kMH  = {-0.5f, -0.5f};
    const v2f k34  = {0.75f, 0.75f};

    for (int rr = 0; rr < TR; ++rr) {
        const float4 cur = xa;
        xa = xb;
        if (rr + 2 < TR) xb = p4[(rr + 2) * 256 + tid];
        const uint4 pl = plane[rr][wz];  // broadcast b128 read, conflict-free
#pragma unroll
        for (int h = 0; h < 2; ++h) {    // pixel pair (2h, 2h+1)
            v2f x;
            x.x = (h == 0) ? cur.x : cur.z;
            x.y = (h == 0) ? cur.y : cur.w;
            const int q0 = sh + (h << 1);

            v2f tf = {(float)((pl.x >> q0) & 1u), (float)((pl.x >> (q0 + 1)) & 1u)};
            v2f f1 = {(float)((pl.y >> q0) & 1u), (float)((pl.y >> (q0 + 1)) & 1u)};
            v2f f2 = {(float)((pl.z >> q0) & 1u), (float)((pl.z >> (q0 + 1)) & 1u)};
            v2f f3 = {(float)((pl.w >> q0) & 1u), (float)((pl.w >> (q0 + 1)) & 1u)};

            v2f ea;
            ea.x = fabsf(x.x) * -1.4426950408889634f;
            ea.y = fabsf(x.y) * -1.4426950408889634f;
            v2f e   = {__builtin_amdgcn_exp2f(ea.x), __builtin_amdgcn_exp2f(ea.y)};
            v2f opl = e + 1.0f;
            v2f inv = {__builtin_amdgcn_rcpf(opl.x), __builtin_amdgcn_rcpf(opl.y)};
            v2f lg  = {__builtin_amdgcn_logf(opl.x), __builtin_amdgcn_logf(opl.y)};
            v2f l1p = lg * 0.6931471805599453f;      // log1p(exp(-|x|))
            v2f pm  = 1.0f - inv;
            v2f p;                                   // sigmoid(x)
            p.x = (x.x >= 0.f) ? inv.x : pm.x;
            p.y = (x.y >= 0.f) ? inv.y : pm.y;

            v2f mx;
            mx.x = fmaxf(x.x, 0.f);
            mx.y = fmaxf(x.y, 0.f);
            v2f ce  = pk_fma(x, -tf, mx + l1p);      // stable BCE-with-logits

            v2f m2p = pk_fma(p, kM2, kP1);
            v2f omp = pk_fma(tf, m2p, p);            // 1 - p_t
            v2f at  = pk_fma(tf, kMH, k34);
            v2f o2  = omp * omp;
            a_f  = pk_fma(o2 * at, ce, a_f);         // focal

            v2f w = pk_fma(f1, dW12, pk_fma(f2, dW23, f3 * cW3));
            a_bw = pk_fma(w, ce, a_bw);
            a_ce += ce;
            a_p  += p;
            a_pt  = pk_fma(tf, p, a_pt);
        }
    }

    // combine packed lanes + popcount-derived sums; deterministic reduction
    float v[7];
    v[0] = a_pt.x + a_pt.y;
    v[1] = a_p.x + a_p.y;
    v[2] = (float)ct;                                   // sum(t)
    v[3] = fmaf((float)c1, W1 - W2,
           fmaf((float)c2, W2 - W3, (float)c3 * W3));   // sum(w)
    v[4] = a_bw.x + a_bw.y;
    v[5] = a_ce.x + a_ce.y;
    v[6] = a_f.x + a_f.y;
#pragma unroll
    for (int off = 1; off < 64; off <<= 1) {
#pragma unroll
        for (int j = 0; j < 7; ++j) v[j] += __shfl_xor(v[j], off);
    }
    if (lane == 0) {
#pragma unroll
        for (int j = 0; j < 7; ++j) red[wid][j] = v[j];
    }
    __syncthreads();
    if (tid < 7) {
        float s = red[0][tid] + red[1][tid] + red[2][tid] + red[3][tid];
        ws[tid * NBLK + blk] = s;
    }
}

// merged per-batch reduction + final scalar math (one launch)
__global__ __launch_bounds__(256) void k_tail(const float* __restrict__ ws,
                                              const float* __restrict__ lv,
                                              float* __restrict__ out) {
    __shared__ float res[7][BATCH];
    const int tid = threadIdx.x;
    const int b   = tid >> 3;          // batch 0..31
    const int g   = tid & 7;           // 8 threads per batch
#pragma unroll
    for (int q = 0; q < 7; ++q) {
        float s = 0.f;
#pragma unroll
        for (int i = 0; i < TILES / 8; ++i) s += ws[q * NBLK + b * TILES + g + i * 8];
        s += __shfl_xor(s, 1);
        s += __shfl_xor(s, 2);
        s += __shfl_xor(s, 4);
        if (g == 0) res[q][b] = s;
    }
    __syncthreads();
    if (tid < 32) {
        const float pt = res[0][tid];
        const float p  = res[1][tid];
        const float t  = res[2][tid];
        const float w  = res[3][tid];
        const float bw = res[4][tid];
        float d  = 1.f - (2.f * pt + 1.f) / (p + t + 1.f);
        float io = 1.f - (pt + 1e-6f) / (p + t - pt + 1e-6f);
        float bn = bw / fmaxf(w, 1.f);
        float ce = res[5][tid];
        float fo = res[6][tid];
#pragma unroll
        for (int off = 1; off < 32; off <<= 1) {
            d  += __shfl_xor(d, off);
            io += __shfl_xor(io, off);
            bn += __shfl_xor(bn, off);
            ce += __shfl_xor(ce, off);
            fo += __shfl_xor(fo, off);
        }
        if (tid == 0) {
            const float N = 33554432.f;   // 32*1024*1024
            float ls[5];
            ls[0] = ce / N;                        // ce
            ls[1] = d * (1.f / 32.f);              // dice
            ls[2] = 0.5f * fo / N;                 // focal
            ls[3] = 0.3f * io * (1.f / 32.f);      // iou
            ls[4] = 0.2f * bn * (1.f / 32.f);      // boundary
            float r[5], s = 0.f;
#pragma unroll
            for (int i = 0; i < 5; ++i) {
                r[i] = 1.f / (1.f + __expf(-lv[i] * (1.f / 1.5f)));
                s += r[i];
            }
            float tot = 0.f;
#pragma unroll
            for (int i = 0; i < 5; ++i) tot += (r[i] / s) * 5.f * ls[i];
            out[0] = tot;
        }
    }
}

extern "C" void kernel_launch(void* const* d_in, const int* in_sizes, int n_in,
                              void* d_out, int out_size, void* d_ws, size_t ws_size,
                              hipStream_t stream) {
    const float* pred = (const float*)d_in[0];
    const float* targ = (const float*)d_in[1];
    const float* lv   = (const float*)d_in[2];
    float* out = (float*)d_out;
    float* ws  = (float*)d_ws;                 // [7][NBLK] partials

    k_main<<<NBLK, 256, 0, stream>>>(pred, targ, ws);
    k_tail<<<1, 256, 0, stream>>>(ws, lv, out);
}